// Round 3
// baseline (134.124 us; speedup 1.0000x reference)
//
#include <hip/hip_runtime.h>
#include <hip/hip_bf16.h>

#define H_DIM 768
#define S_LEN 128
#define BK 64
#define NT 12  // 768 / 64 K-tiles

typedef __attribute__((ext_vector_type(8))) short short8;
typedef __attribute__((ext_vector_type(4))) float f32x4;

__device__ __forceinline__ void gload_lds16(const void* g, void* l) {
  __builtin_amdgcn_global_load_lds(
      (const __attribute__((address_space(1))) unsigned int*)g,
      (__attribute__((address_space(3))) unsigned int*)l, 16, 0, 0);
}

// ---------------- Kernel 1: per-token L2 normalize, fp32 -> bf16 (both tensors) ----------------
__global__ __launch_bounds__(256) void norm_bf16_kernel(
    const float* __restrict__ x1, const float* __restrict__ x2,
    unsigned short* __restrict__ xn1, unsigned short* __restrict__ xn2) {
  const int gid = blockIdx.x;
  const float* row;
  unsigned short* orow;
  if (gid < 8192) { row = x1 + (size_t)gid * H_DIM; orow = xn1 + (size_t)gid * H_DIM; }
  else            { row = x2 + (size_t)(gid - 8192) * H_DIM; orow = xn2 + (size_t)(gid - 8192) * H_DIM; }
  const int tid = threadIdx.x;
  float4 v = make_float4(0.f, 0.f, 0.f, 0.f);
  float ss = 0.f;
  if (tid < 192) {  // 192 * 4 = 768 floats
    v = reinterpret_cast<const float4*>(row)[tid];
    ss = v.x * v.x + v.y * v.y + v.z * v.z + v.w * v.w;
  }
#pragma unroll
  for (int o = 32; o > 0; o >>= 1) ss += __shfl_down(ss, o);
  __shared__ float ws[4];
  if ((tid & 63) == 0) ws[tid >> 6] = ss;
  __syncthreads();
  const float scale = 1.0f / sqrtf(ws[0] + ws[1] + ws[2] + ws[3]);
  if (tid < 192) {
    union { ushort4 u; __hip_bfloat16 h[4]; } o;
    o.h[0] = __float2bfloat16(v.x * scale);
    o.h[1] = __float2bfloat16(v.y * scale);
    o.h[2] = __float2bfloat16(v.z * scale);
    o.h[3] = __float2bfloat16(v.w * scale);
    reinterpret_cast<ushort4*>(orow)[tid] = o.u;
  }
}

// stage one 256x64 A-tile + 256x64 B-tile (8 gload_lds / thread). Linear LDS
// dest (gload_lds requirement), inverse-swizzled GLOBAL source (rule 21).
__device__ __forceinline__ void stage_tile(const unsigned short* __restrict__ gA,
                                           const unsigned short* __restrict__ gB,
                                           unsigned short* lA, unsigned short* lB,
                                           int tid, int k0) {
#pragma unroll
  for (int c = 0; c < 4; ++c) {
    const int s = c * 512 + tid;
    const int row = s >> 3;
    const int cb = (s & 7) ^ (row & 7);
    gload_lds16(gA + (size_t)row * H_DIM + k0 + cb * 8, lA + s * 8);
  }
#pragma unroll
  for (int c = 0; c < 4; ++c) {
    const int s = c * 512 + tid;
    const int row = s >> 3;
    const int cb = (s & 7) ^ (row & 7);
    gload_lds16(gB + (size_t)row * H_DIM + k0 + cb * 8, lB + s * 8);
  }
}

// ---------------- Kernel 2: one block = (2 a's) x (2 b's), 256x256 tile ----------------
// 8 waves 2x4: wave (wm,wn) owns rows wm*128..+128, cols wn*64..+64.
// Double-buffered LDS + counted-vmcnt pipeline (T3/T4): prefetch 2 K-tiles
// deep, raw s_barrier with explicit lgkmcnt(0); vmcnt(8) keeps next tile's
// loads in flight across the barrier (never vmcnt(0) mid-loop).
__global__ __launch_bounds__(512, 2) void rwmd_kernel(
    const unsigned short* __restrict__ xn1, const unsigned short* __restrict__ xn2,
    const int* __restrict__ mask1, const int* __restrict__ mask2,
    float* __restrict__ out) {
  extern __shared__ __align__(16) unsigned short dynlds[];  // 128 KB
  unsigned short* const A0l = dynlds;
  unsigned short* const A1l = dynlds + 256 * BK;
  unsigned short* const B0l = dynlds + 2 * 256 * BK;
  unsigned short* const B1l = dynlds + 3 * 256 * BK;
  __shared__ int m1s[256], m2s[256];
  __shared__ float rpart[4][256];  // [wn][row] partial row-max
  __shared__ float cpart[2][256];  // [wm][col] partial col-max

  const int ap = blockIdx.x >> 5;   // 32 a-pairs
  const int bp = blockIdx.x & 31;   // 32 b-pairs
  const int tid = threadIdx.x;
  const int lane = tid & 63;
  const int w = tid >> 6;
  const int wm = w >> 2, wn = w & 3;
  const int g = lane >> 4, rl = lane & 15;

  const unsigned short* Ag = xn1 + (size_t)ap * (2 * S_LEN * H_DIM);  // 256 rows
  const unsigned short* Bg = xn2 + (size_t)bp * (2 * S_LEN * H_DIM);  // 256 rows

  if (tid < 256) m1s[tid] = mask1[ap * 256 + tid];
  else           m2s[tid - 256] = mask2[bp * 256 + (tid - 256)];

  f32x4 acc[8][4];
#pragma unroll
  for (int i = 0; i < 8; ++i)
#pragma unroll
    for (int j = 0; j < 4; ++j) acc[i][j] = (f32x4){0.f, 0.f, 0.f, 0.f};

  // prologue: tiles 0 and 1 in flight
  stage_tile(Ag, Bg, A0l, B0l, tid, 0);
  stage_tile(Ag, Bg, A1l, B1l, tid, BK);
  asm volatile("s_waitcnt vmcnt(8)" ::: "memory");  // tile 0 (and masks) landed
  __builtin_amdgcn_s_barrier();

  for (int kt = 0; kt < NT; ++kt) {
    unsigned short* const lA = (kt & 1) ? A1l : A0l;
    unsigned short* const lB = (kt & 1) ? B1l : B0l;
#pragma unroll
    for (int kf = 0; kf < 2; ++kf) {
      short8 av[8], bv[4];
#pragma unroll
      for (int i = 0; i < 8; ++i) {
        const int r = wm * 128 + i * 16 + rl;
        const int slot = (kf * 4 + g) ^ (r & 7);  // swizzled read
        av[i] = *reinterpret_cast<const short8*>(&lA[r * BK + slot * 8]);
      }
#pragma unroll
      for (int j = 0; j < 4; ++j) {
        const int r = wn * 64 + j * 16 + rl;
        const int slot = (kf * 4 + g) ^ (r & 7);
        bv[j] = *reinterpret_cast<const short8*>(&lB[r * BK + slot * 8]);
      }
#pragma unroll
      for (int i = 0; i < 8; ++i)
#pragma unroll
        for (int j = 0; j < 4; ++j)
          acc[i][j] = __builtin_amdgcn_mfma_f32_16x16x32_bf16(av[i], bv[j], acc[i][j], 0, 0, 0);
    }
    if (kt == NT - 1) break;
    asm volatile("s_waitcnt lgkmcnt(0)" ::: "memory");  // my ds_reads retired
    __builtin_amdgcn_s_barrier();                       // everyone done reading buf[cur]
    if (kt + 2 < NT) {
      stage_tile(Ag, Bg, lA, lB, tid, (kt + 2) * BK);   // overwrite freed buffer
      asm volatile("s_waitcnt vmcnt(8)" ::: "memory");  // kt+1 landed; kt+2 in flight
    } else {
      asm volatile("s_waitcnt vmcnt(0)" ::: "memory");  // tail: kt+1 landed
    }
    __builtin_amdgcn_s_barrier();
  }

  // ---- in-register masked reductions ----
  // acc[i][j][r]: row = wm*128 + i*16 + g*4 + r, col = wn*64 + j*16 + rl
#pragma unroll
  for (int i = 0; i < 8; ++i) {
#pragma unroll
    for (int r = 0; r < 4; ++r) {
      float pm = -INFINITY;
#pragma unroll
      for (int j = 0; j < 4; ++j) {
        const int col = wn * 64 + j * 16 + rl;
        pm = fmaxf(pm, m2s[col] ? acc[i][j][r] : -INFINITY);
      }
#pragma unroll
      for (int o = 1; o < 16; o <<= 1) pm = fmaxf(pm, __shfl_xor(pm, o));
      if (rl == 0) rpart[wn][wm * 128 + i * 16 + g * 4 + r] = pm;
    }
  }
#pragma unroll
  for (int j = 0; j < 4; ++j) {
    float cm = -INFINITY;
#pragma unroll
    for (int i = 0; i < 8; ++i)
#pragma unroll
      for (int r = 0; r < 4; ++r) {
        const int row = wm * 128 + i * 16 + g * 4 + r;
        cm = fmaxf(cm, m1s[row] ? acc[i][j][r] : -INFINITY);
      }
    cm = fmaxf(cm, __shfl_xor(cm, 16));
    cm = fmaxf(cm, __shfl_xor(cm, 32));
    if (g == 0) cpart[wm][wn * 64 + j * 16 + rl] = cm;
  }
  __syncthreads();

  // ---- final masked means: wave w -> pair (ai=w>>1, bj=w&1) ----
  if (w < 4) {
    const int ai = w >> 1, bj = w & 1;
    float v1 = 0.f, c1 = 0.f, v2 = 0.f, c2 = 0.f;
#pragma unroll
    for (int t = 0; t < 2; ++t) {
      const int row = ai * 128 + lane + t * 64;
      if (m1s[row]) { v1 += fmaxf(rpart[2 * bj][row], rpart[2 * bj + 1][row]); c1 += 1.f; }
      const int col = bj * 128 + lane + t * 64;
      if (m2s[col]) { v2 += cpart[ai][col]; c2 += 1.f; }
    }
#pragma unroll
    for (int o = 32; o > 0; o >>= 1) {
      v1 += __shfl_down(v1, o); c1 += __shfl_down(c1, o);
      v2 += __shfl_down(v2, o); c2 += __shfl_down(c2, o);
    }
    if (lane == 0) out[(ap * 2 + ai) * 64 + bp * 2 + bj] = 0.5f * (v1 / c1 + v2 / c2);
  }
}

extern "C" void kernel_launch(void* const* d_in, const int* in_sizes, int n_in,
                              void* d_out, int out_size, void* d_ws, size_t ws_size,
                              hipStream_t stream) {
  const float* x1 = (const float*)d_in[0];
  const int* mask1 = (const int*)d_in[1];
  const float* x2 = (const float*)d_in[2];
  const int* mask2 = (const int*)d_in[3];
  float* out = (float*)d_out;

  unsigned short* xn1 = (unsigned short*)d_ws;         // 64*128*768 bf16
  unsigned short* xn2 = xn1 + (size_t)64 * 128 * 768;  // 12.6 MB each

  hipFuncSetAttribute((const void*)rwmd_kernel,
                      hipFuncAttributeMaxDynamicSharedMemorySize, 128 * 1024);

  norm_bf16_kernel<<<16384, 256, 0, stream>>>(x1, x2, xn1, xn2);
  rwmd_kernel<<<32 * 32, 512, 128 * 1024, stream>>>(xn1, xn2, mask1, mask2, out);
}

// Round 4
// 130.367 us; speedup vs baseline: 1.0288x; 1.0288x over previous
//
#include <hip/hip_runtime.h>
#include <hip/hip_bf16.h>

#define H_DIM 768
#define S_LEN 128
#define BK 64
#define NT 12    // 768 / 64 K-tiles
#define NITER 6  // 2 K-tiles per 8-phase iteration

typedef __attribute__((ext_vector_type(8))) short short8;
typedef __attribute__((ext_vector_type(4))) float f32x4;

__device__ __forceinline__ void gload_lds16(const void* g, void* l) {
  __builtin_amdgcn_global_load_lds(
      (const __attribute__((address_space(1))) unsigned int*)g,
      (__attribute__((address_space(3))) unsigned int*)l, 16, 0, 0);
}

// ---------------- Kernel 1: per-token L2 normalize, fp32 -> bf16 (both tensors) ----------------
__global__ __launch_bounds__(256) void norm_bf16_kernel(
    const float* __restrict__ x1, const float* __restrict__ x2,
    unsigned short* __restrict__ xn1, unsigned short* __restrict__ xn2) {
  const int gid = blockIdx.x;
  const float* row;
  unsigned short* orow;
  if (gid < 8192) { row = x1 + (size_t)gid * H_DIM; orow = xn1 + (size_t)gid * H_DIM; }
  else            { row = x2 + (size_t)(gid - 8192) * H_DIM; orow = xn2 + (size_t)(gid - 8192) * H_DIM; }
  const int tid = threadIdx.x;
  float4 v = make_float4(0.f, 0.f, 0.f, 0.f);
  float ss = 0.f;
  if (tid < 192) {
    v = reinterpret_cast<const float4*>(row)[tid];
    ss = v.x * v.x + v.y * v.y + v.z * v.z + v.w * v.w;
  }
#pragma unroll
  for (int o = 32; o > 0; o >>= 1) ss += __shfl_down(ss, o);
  __shared__ float ws[4];
  if ((tid & 63) == 0) ws[tid >> 6] = ss;
  __syncthreads();
  const float scale = 1.0f / sqrtf(ws[0] + ws[1] + ws[2] + ws[3]);
  if (tid < 192) {
    union { ushort4 u; __hip_bfloat16 h[4]; } o;
    o.h[0] = __float2bfloat16(v.x * scale);
    o.h[1] = __float2bfloat16(v.y * scale);
    o.h[2] = __float2bfloat16(v.z * scale);
    o.h[3] = __float2bfloat16(v.w * scale);
    reinterpret_cast<ushort4*>(orow)[tid] = o.u;
  }
}

// stage one 128-row half-tile (16 KB, 2 gload_lds/thread). Linear LDS dest
// (gload_lds requirement), inverse-swizzled GLOBAL source chunk (rule 21).
__device__ __forceinline__ void stage_half(const unsigned short* __restrict__ g,
                                           unsigned short* l, int tid, int k0,
                                           int rowbase) {
#pragma unroll
  for (int q = 0; q < 2; ++q) {
    const int s = q * 512 + tid;            // chunk 0..1023 within the half
    const int lrow = rowbase + (s >> 3);    // panel-local row 0..255
    const int cb = (s & 7) ^ (lrow & 7);    // inverse-swizzled source chunk
    gload_lds16(g + (size_t)lrow * H_DIM + k0 + cb * 8, l + lrow * 64 + (s & 7) * 8);
  }
}

// One phase: {ds_read subtile | stage 1 half-tile | barrier | lgkm0 | 16 MFMA | [vmcnt] | barrier}
// Wave rows: row = IH*128 + wm*64 + i*16 (+g*4+reg); so phase IH reads A-half IH only.
// bv[kf] fragments are read in the two READBV phases and held in registers after.
#define PHASE(LA, LB, IH, KF, READBV, STAGE, VM)                                \
  {                                                                             \
    short8 av[4];                                                               \
    _Pragma("unroll")                                                           \
    for (int i = 0; i < 4; ++i) {                                               \
      const int r = IH * 128 + wm * 64 + i * 16 + rl;                           \
      const int slot = (KF * 4 + g) ^ (r & 7);                                  \
      av[i] = *reinterpret_cast<const short8*>(&LA[r * 64 + slot * 8]);         \
    }                                                                           \
    if (READBV) {                                                               \
      _Pragma("unroll")                                                         \
      for (int j = 0; j < 4; ++j) {                                             \
        const int r = wn * 64 + j * 16 + rl;                                    \
        const int slot = (KF * 4 + g) ^ (r & 7);                                \
        bv[KF][j] = *reinterpret_cast<const short8*>(&LB[r * 64 + slot * 8]);   \
      }                                                                         \
    }                                                                           \
    STAGE;                                                                      \
    __builtin_amdgcn_s_barrier();                                               \
    asm volatile("s_waitcnt lgkmcnt(0)" ::: "memory");                          \
    __builtin_amdgcn_sched_barrier(0);                                          \
    __builtin_amdgcn_s_setprio(1);                                              \
    _Pragma("unroll")                                                           \
    for (int i = 0; i < 4; ++i)                                                 \
      _Pragma("unroll")                                                         \
      for (int j = 0; j < 4; ++j)                                               \
        acc[IH * 4 + i][j] = __builtin_amdgcn_mfma_f32_16x16x32_bf16(           \
            av[i], bv[KF][j], acc[IH * 4 + i][j], 0, 0, 0);                     \
    __builtin_amdgcn_s_setprio(0);                                              \
    VM;                                                                         \
    __builtin_amdgcn_s_barrier();                                               \
  }

// ---------------- Kernel 2: (2 a's) x (2 b's) = 256x256 tile, m201-style 8-phase ----------------
__global__ __launch_bounds__(512, 2) void rwmd_kernel(
    const unsigned short* __restrict__ xn1, const unsigned short* __restrict__ xn2,
    const int* __restrict__ mask1, const int* __restrict__ mask2,
    float* __restrict__ out) {
  extern __shared__ __align__(16) unsigned short dynlds[];  // 128 KB
  unsigned short* const Ab0 = dynlds;           // even K-tile A [256][64]
  unsigned short* const Ab1 = dynlds + 16384;   // odd  K-tile A
  unsigned short* const Bb0 = dynlds + 32768;   // even K-tile B
  unsigned short* const Bb1 = dynlds + 49152;   // odd  K-tile B
  __shared__ int m1s[256], m2s[256];
  __shared__ float rpart[4][256];     // [wn][row] partial row-max
  __shared__ float cpart[2][2][256];  // [wm][ih(=ai)][col] partial col-max

  const int ap = blockIdx.x >> 5;
  const int bp = blockIdx.x & 31;
  const int tid = threadIdx.x;
  const int lane = tid & 63;
  const int w = tid >> 6;
  const int wm = w >> 2, wn = w & 3;
  const int g = lane >> 4, rl = lane & 15;

  const unsigned short* Ag = xn1 + (size_t)ap * (2 * S_LEN * H_DIM);  // 256 rows
  const unsigned short* Bg = xn2 + (size_t)bp * (2 * S_LEN * H_DIM);  // 256 rows

  if (tid < 256) m1s[tid] = mask1[ap * 256 + tid];
  else           m2s[tid - 256] = mask2[bp * 256 + (tid - 256)];

  f32x4 acc[8][4];
#pragma unroll
  for (int i = 0; i < 8; ++i)
#pragma unroll
    for (int j = 0; j < 4; ++j) acc[i][j] = (f32x4){0.f, 0.f, 0.f, 0.f};
  short8 bv[2][4];

  // prologue: tile 0 complete + B halves of tile 1 (12 loads; drain tile 0, B(1) flies)
  stage_half(Ag, Ab0, tid, 0, 0);
  stage_half(Ag, Ab0, tid, 0, 128);
  stage_half(Bg, Bb0, tid, 0, 0);
  stage_half(Bg, Bb0, tid, 0, 128);
  stage_half(Bg, Bb1, tid, BK, 0);
  stage_half(Bg, Bb1, tid, BK, 128);
  asm volatile("s_waitcnt vmcnt(4) lgkmcnt(0)" ::: "memory");  // lgkm: mask ds_writes
  __builtin_amdgcn_s_barrier();

#pragma unroll 1
  for (int t = 0; t < NITER; ++t) {
    const int kA = (2 * t + 1) * BK;  // odd tile (computed this iter, ph5-8)
    const int kB = (2 * t + 2) * BK;  // next even tile
    const int kC = (2 * t + 3) * BK;  // next odd tile (B halves only)
    const bool more = (t < NITER - 1);
    // phases 1-4: compute even tile 2t (Ab0/Bb0)
    PHASE(Ab0, Bb0, 0, 0, true,  { stage_half(Ag, Ab1, tid, kA, 0); }, {});
    PHASE(Ab0, Bb0, 0, 1, true,  { stage_half(Ag, Ab1, tid, kA, 128); }, {});
    PHASE(Ab0, Bb0, 1, 0, false, { if (more) stage_half(Ag, Ab0, tid, kB, 0); }, {});
    PHASE(Ab0, Bb0, 1, 1, false, { if (more) stage_half(Bg, Bb0, tid, kB, 0); },
          { if (more) asm volatile("s_waitcnt vmcnt(4)" ::: "memory");
            else      asm volatile("s_waitcnt vmcnt(0)" ::: "memory"); });
    // phases 5-8: compute odd tile 2t+1 (Ab1/Bb1)
    PHASE(Ab1, Bb1, 0, 0, true,  { if (more) stage_half(Bg, Bb0, tid, kB, 128); }, {});
    PHASE(Ab1, Bb1, 0, 1, true,  { if (more) stage_half(Ag, Ab0, tid, kB, 128); }, {});
    PHASE(Ab1, Bb1, 1, 0, false, { if (more) stage_half(Bg, Bb1, tid, kC, 0); }, {});
    PHASE(Ab1, Bb1, 1, 1, false, { if (more) stage_half(Bg, Bb1, tid, kC, 128); },
          { if (more) asm volatile("s_waitcnt vmcnt(4)" ::: "memory"); });
  }

  // ---- in-register masked reductions ----
  // acc[ih*4+i][j][r]: row = ih*128 + wm*64 + i*16 + g*4 + r, col = wn*64 + j*16 + rl
#pragma unroll
  for (int ih = 0; ih < 2; ++ih)
#pragma unroll
    for (int i = 0; i < 4; ++i) {
#pragma unroll
      for (int r = 0; r < 4; ++r) {
        float pm = -INFINITY;
#pragma unroll
        for (int j = 0; j < 4; ++j) {
          const int col = wn * 64 + j * 16 + rl;
          pm = fmaxf(pm, m2s[col] ? acc[ih * 4 + i][j][r] : -INFINITY);
        }
#pragma unroll
        for (int o = 1; o < 16; o <<= 1) pm = fmaxf(pm, __shfl_xor(pm, o));
        if (rl == 0) rpart[wn][ih * 128 + wm * 64 + i * 16 + g * 4 + r] = pm;
      }
    }
#pragma unroll
  for (int j = 0; j < 4; ++j)
#pragma unroll
    for (int ih = 0; ih < 2; ++ih) {
      float cm = -INFINITY;
#pragma unroll
      for (int i = 0; i < 4; ++i)
#pragma unroll
        for (int r = 0; r < 4; ++r) {
          const int row = ih * 128 + wm * 64 + i * 16 + g * 4 + r;
          cm = fmaxf(cm, m1s[row] ? acc[ih * 4 + i][j][r] : -INFINITY);
        }
      cm = fmaxf(cm, __shfl_xor(cm, 16));
      cm = fmaxf(cm, __shfl_xor(cm, 32));
      if (g == 0) cpart[wm][ih][wn * 64 + j * 16 + rl] = cm;
    }
  __syncthreads();

  // ---- final masked means: wave w -> pair (ai=w>>1, bj=w&1) ----
  if (w < 4) {
    const int ai = w >> 1, bj = w & 1;
    float v1 = 0.f, c1 = 0.f, v2 = 0.f, c2 = 0.f;
#pragma unroll
    for (int tt = 0; tt < 2; ++tt) {
      const int row = ai * 128 + tt * 64 + lane;
      if (m1s[row]) { v1 += fmaxf(rpart[2 * bj][row], rpart[2 * bj + 1][row]); c1 += 1.f; }
      const int col = bj * 128 + tt * 64 + lane;
      if (m2s[col]) { v2 += fmaxf(cpart[0][ai][col], cpart[1][ai][col]); c2 += 1.f; }
    }
#pragma unroll
    for (int o = 32; o > 0; o >>= 1) {
      v1 += __shfl_down(v1, o); c1 += __shfl_down(c1, o);
      v2 += __shfl_down(v2, o); c2 += __shfl_down(c2, o);
    }
    if (lane == 0) out[(ap * 2 + ai) * 64 + bp * 2 + bj] = 0.5f * (v1 / c1 + v2 / c2);
  }
}

extern "C" void kernel_launch(void* const* d_in, const int* in_sizes, int n_in,
                              void* d_out, int out_size, void* d_ws, size_t ws_size,
                              hipStream_t stream) {
  const float* x1 = (const float*)d_in[0];
  const int* mask1 = (const int*)d_in[1];
  const float* x2 = (const float*)d_in[2];
  const int* mask2 = (const int*)d_in[3];
  float* out = (float*)d_out;

  unsigned short* xn1 = (unsigned short*)d_ws;
  unsigned short* xn2 = xn1 + (size_t)64 * 128 * 768;

  hipFuncSetAttribute((const void*)rwmd_kernel,
                      hipFuncAttributeMaxDynamicSharedMemorySize, 128 * 1024);

  norm_bf16_kernel<<<16384, 256, 0, stream>>>(x1, x2, xn1, xn2);
  rwmd_kernel<<<32 * 32, 512, 128 * 1024, stream>>>(xn1, xn2, mask1, mask2, out);
}